// Round 10
// baseline (345.929 us; speedup 1.0000x reference)
//
#include <hip/hip_runtime.h>

#define E0     300000
#define E1     75000
#define NSRC0  50000
#define NDST0  20000
#define NDST1  5000
#define EMB    128
#define HID    256
#define NOUT   16

#define NPB        16     // nodes per embed block (3125 * 16 = 50000 exactly)
#define TILE_SHIFT 12     // 4096-row vocab tiles; tiles 0..12

// ---- bf16 helpers (RNE pack, cheap unpack) ----
__device__ __forceinline__ unsigned short f2bf(float f) {
    unsigned u = __float_as_uint(f);
    return (unsigned short)((u + 0x7FFFu + ((u >> 16) & 1u)) >> 16);
}
__device__ __forceinline__ float bflo(unsigned u) { return __uint_as_float(u << 16); }
__device__ __forceinline__ float bfhi(unsigned u) { return __uint_as_float(u & 0xFFFF0000u); }
__device__ __forceinline__ unsigned pack2(float a, float b) {
    return (unsigned)f2bf(a) | ((unsigned)f2bf(b) << 16);
}

// ---------------- prep: f32->bf16 table conv + degree histograms, fused ----------------
__global__ void prep_kernel(const float* __restrict__ wt, unsigned short* __restrict__ wtb,
                            const int* __restrict__ src0, const int* __restrict__ dst0,
                            const int* __restrict__ src1, const int* __restrict__ dst1,
                            int* cnt0, int* cnt1, int* degO0, int* degO1) {
    int i = blockIdx.x * blockDim.x + threadIdx.x;
    if (i < NSRC0 * EMB / 8) {            // 800000: pack 8 floats -> 8 bf16
        const float4* in = (const float4*)wt;
        float4 v0 = in[i * 2], v1 = in[i * 2 + 1];
        uint4 o;
        o.x = pack2(v0.x, v0.y); o.y = pack2(v0.z, v0.w);
        o.z = pack2(v1.x, v1.y); o.w = pack2(v1.z, v1.w);
        ((uint4*)wtb)[i] = o;
    }
    if (i < E0) {
        atomicAdd(&cnt0[dst0[i]], 1);
        atomicAdd(&degO0[src0[i]], 1);
    }
    if (i < E1) {
        atomicAdd(&cnt1[dst1[i]], 1);
        atomicAdd(&degO1[src1[i]], 1);
    }
}

// ---------------- exclusive scan (2 blocks x 1024 threads) ----------------
__device__ void scan_body(const int* __restrict__ cnt, int n,
                          int* __restrict__ off, int* __restrict__ cur) {
    __shared__ int sums[1024];
    int t = threadIdx.x;
    int chunk = (n + 1023) / 1024;
    int lo = t * chunk, hi = min(lo + chunk, n);
    int s = 0;
    for (int i = lo; i < hi; ++i) s += cnt[i];
    sums[t] = s;
    __syncthreads();
    for (int d = 1; d < 1024; d <<= 1) {
        int x = (t >= d) ? sums[t - d] : 0;
        __syncthreads();
        sums[t] += x;
        __syncthreads();
    }
    int run = (t == 0) ? 0 : sums[t - 1];
    for (int i = lo; i < hi; ++i) {
        off[i] = run; cur[i] = run;
        run += cnt[i];
    }
    if (t == 1023) off[n] = run;
}

__global__ void scan_kernel(const int* cnt0, int* off0, int* cur0,
                            const int* cnt1, int* off1, int* cur1) {
    if (blockIdx.x == 0) scan_body(cnt0, NDST0, off0, cur0);
    else                 scan_body(cnt1, NDST1, off1, cur1);
}

// ---------------- bucket edges by dst (build CSR adjacency) ----------------
__global__ void bucket_kernel(const int* __restrict__ src0, const int* __restrict__ dst0,
                              const int* __restrict__ src1, const int* __restrict__ dst1,
                              int* cur0, int* cur1, int* esrc0, int* esrc1) {
    int i = blockIdx.x * blockDim.x + threadIdx.x;
    if (i < E0) {
        int p = atomicAdd(&cur0[dst0[i]], 1);
        esrc0[p] = src0[i];
    }
    if (i < E1) {
        int p = atomicAdd(&cur1[dst1[i]], 1);
        esrc1[p] = src1[i];
    }
}

// ---------------- fused embedding mean: LDS tile-sort + bf16 gather -------
// 3125 blocks x 16 nodes: full occupancy (8 blocks/CU, 7.5KB LDS each).
__global__ void embed_kernel(const int* __restrict__ user_word,
                             const unsigned short* __restrict__ wtb,
                             const int* __restrict__ degO0,
                             unsigned short* __restrict__ x0b) {
    __shared__ int raw[NPB * 50];
    __shared__ int srt[NPB * 50];
    __shared__ int cnt[NPB * 17];        // stride 17: avoids LDS bank conflicts
    int t = threadIdx.x;
    int base = blockIdx.x * NPB * 50;
    for (int j = t; j < NPB * 50; j += 256)
        raw[j] = user_word[base + j];
    for (int j = t; j < NPB * 17; j += 256)
        cnt[j] = 0;
    __syncthreads();
    if (t < NPB) {                                // 1 thread sorts 1 node (in LDS)
        int* c = cnt + t * 17;
        const int* r = raw + t * 50;
        for (int j = 0; j < 50; ++j) c[r[j] >> TILE_SHIFT]++;
        int run = 0;
        for (int b = 0; b < 13; ++b) { int v = c[b]; c[b] = run; run += v; }
        int* o = srt + t * 50;
        for (int j = 0; j < 50; ++j) { int v = r[j]; o[c[v >> TILE_SHIFT]++] = v; }
    }
    __syncthreads();
    int g = t >> 5, l = t & 31;                   // 8 groups of 32 lanes
    const uint2* wt2 = (const uint2*)wtb;         // row = 32 uint2
    for (int n = g; n < NPB; n += 8) {            // 2 nodes per group
        const int* id = srt + n * 50;
        float a0 = 0.f, a1 = 0.f, a2 = 0.f, a3 = 0.f;
        #pragma unroll 2
        for (int j = 0; j < 50; j += 2) {
            uint2 v0 = wt2[id[j] * 32 + l];
            uint2 v1 = wt2[id[j + 1] * 32 + l];
            a0 += bflo(v0.x) + bflo(v1.x); a1 += bfhi(v0.x) + bfhi(v1.x);
            a2 += bflo(v0.y) + bflo(v1.y); a3 += bfhi(v0.y) + bfhi(v1.y);
        }
        int node = blockIdx.x * NPB + n;
        float s = rsqrtf(fmaxf((float)degO0[node], 1.0f)) * 0.02f;  // 1/50 mean
        uint2 o2; o2.x = pack2(a0 * s, a1 * s); o2.y = pack2(a2 * s, a3 * s);
        ((uint2*)x0b)[node * 32 + l] = o2;
    }
}

// ---------------- layer-1 gather-aggregate (bf16 in/out, 4 dst per 256-thr block) ----
// Wave w owns dst 4*blk+w; no barriers. 256-thr blocks lift the 16-wg/CU occupancy cap.
__global__ void agg1_kernel(const int* __restrict__ off0, const int* __restrict__ esrc0,
                            const unsigned short* __restrict__ x0b,
                            unsigned short* __restrict__ agg1b) {
    int t = threadIdx.x;
    int d = blockIdx.x * 4 + (t >> 6);             // 5000 blocks * 4 = 20000
    int lane = t & 63;
    int half = lane >> 5, l = lane & 31;
    int lo = off0[d], hi = off0[d + 1];
    const uint2* x2 = (const uint2*)x0b;           // row = 32 uint2
    float a0 = 0.f, a1 = 0.f, a2 = 0.f, a3 = 0.f;
    for (int j = lo + half; j < hi; j += 2) {
        uint2 v = x2[esrc0[j] * 32 + l];
        a0 += bflo(v.x); a1 += bfhi(v.x); a2 += bflo(v.y); a3 += bfhi(v.y);
    }
    a0 += __shfl_down(a0, 32); a1 += __shfl_down(a1, 32);
    a2 += __shfl_down(a2, 32); a3 += __shfl_down(a3, 32);
    if (half == 0) {
        float sc = rsqrtf(fmaxf((float)(hi - lo), 1.0f));
        uint2 o; o.x = pack2(a0 * sc, a1 * sc); o.y = pack2(a2 * sc, a3 * sc);
        ((uint2*)agg1b)[d * 32 + l] = o;
    }
}

// ---------------- GEMM1: h1 = relu(agg1 @ W1 + b1) * rsqrt(deg_out1), bf16 out ------
__global__ void gemm1_kernel(const unsigned short* __restrict__ agg1b,
                             const int* __restrict__ degO1,
                             const float* __restrict__ W1, const float* __restrict__ b1,
                             unsigned short* __restrict__ h1b) {
    __shared__ float A[16 * 132];     // pad 132 (%4==0: aligned float4 rows)
    __shared__ float s_out[16];
    int t = threadIdx.x;
    int row0 = blockIdx.x * 16;
    if (t < 16) s_out[t] = rsqrtf(fmaxf((float)degO1[row0 + t], 1.0f));
    const unsigned* ag = (const unsigned*)agg1b + row0 * 64;   // 16 rows x 64 uint
    for (int j = t; j < 16 * 64; j += 256) {
        unsigned v = ag[j];
        int r = j >> 6, p = j & 63;
        A[r * 132 + 2 * p]     = bflo(v);
        A[r * 132 + 2 * p + 1] = bfhi(v);
    }
    __syncthreads();
    float acc[16];
    #pragma unroll
    for (int r = 0; r < 16; ++r) acc[r] = 0.f;
    for (int k4 = 0; k4 < 32; ++k4) {
        float w0 = W1[(k4 * 4 + 0) * 256 + t];     // coalesced across t
        float w1 = W1[(k4 * 4 + 1) * 256 + t];
        float w2 = W1[(k4 * 4 + 2) * 256 + t];
        float w3 = W1[(k4 * 4 + 3) * 256 + t];
        #pragma unroll
        for (int r = 0; r < 16; ++r) {
            float4 a = *(const float4*)(A + r * 132 + k4 * 4);  // b128 broadcast
            acc[r] += a.x * w0 + a.y * w1 + a.z * w2 + a.w * w3;
        }
    }
    float bb = b1[t];
    #pragma unroll
    for (int r = 0; r < 16; ++r)
        h1b[(row0 + r) * 256 + t] = f2bf(fmaxf(acc[r] + bb, 0.f) * s_out[r]);
}

// ---------------- layer-2 gather-aggregate (bf16 in/out, 4 dst per 256-thr block) ----
__global__ void agg2_kernel(const int* __restrict__ off1, const int* __restrict__ esrc1,
                            const unsigned short* __restrict__ h1b,
                            unsigned short* __restrict__ agg2b) {
    int t = threadIdx.x;
    int d = blockIdx.x * 4 + (t >> 6);             // 1250 blocks * 4 = 5000
    int l = t & 63;
    int lo = off1[d], hi = off1[d + 1];
    const uint2* h2 = (const uint2*)h1b;           // row = 64 uint2
    float a0 = 0.f, a1 = 0.f, a2 = 0.f, a3 = 0.f;
    int j = lo;
    for (; j + 1 < hi; j += 2) {
        uint2 v0 = h2[esrc1[j] * 64 + l];
        uint2 v1 = h2[esrc1[j + 1] * 64 + l];
        a0 += bflo(v0.x) + bflo(v1.x); a1 += bfhi(v0.x) + bfhi(v1.x);
        a2 += bflo(v0.y) + bflo(v1.y); a3 += bfhi(v0.y) + bfhi(v1.y);
    }
    if (j < hi) {
        uint2 v = h2[esrc1[j] * 64 + l];
        a0 += bflo(v.x); a1 += bfhi(v.x); a2 += bflo(v.y); a3 += bfhi(v.y);
    }
    float sc = rsqrtf(fmaxf((float)(hi - lo), 1.0f));
    uint2 o; o.x = pack2(a0 * sc, a1 * sc); o.y = pack2(a2 * sc, a3 * sc);
    ((uint2*)agg2b)[d * 64 + l] = o;
}

// ---------------- GEMM2: out = relu(agg2 @ W2 + b2)  (+ labels passthrough) ----------
__global__ void gemm2_kernel(const unsigned short* __restrict__ agg2b,
                             const float* __restrict__ W2, const float* __restrict__ b2,
                             const int* __restrict__ labels,
                             float* __restrict__ out) {
    __shared__ float A[16 * 260];     // pad 260 (%4==0, breaks 16-way bank stride)
    __shared__ float Wl[256 * 16];
    int t = threadIdx.x;
    int row0 = blockIdx.x * 16;
    for (int j = t; j < 256 * 16; j += 256) Wl[j] = W2[j];
    const unsigned* ag = (const unsigned*)agg2b + row0 * 128;  // 16 rows x 128 uint
    for (int j = t; j < 16 * 128; j += 256) {
        int r = j >> 7, p = j & 127;
        unsigned v = (row0 + r < NDST1) ? ag[j] : 0u;
        A[r * 260 + 2 * p]     = bflo(v);
        A[r * 260 + 2 * p + 1] = bfhi(v);
    }
    __syncthreads();
    int r = t >> 4, c = t & 15;
    float acc = 0.0f;
    for (int k4 = 0; k4 < 64; ++k4) {
        float4 a = *(const float4*)(A + r * 260 + k4 * 4);     // b128
        acc += a.x * Wl[(k4 * 4 + 0) * 16 + c] + a.y * Wl[(k4 * 4 + 1) * 16 + c]
             + a.z * Wl[(k4 * 4 + 2) * 16 + c] + a.w * Wl[(k4 * 4 + 3) * 16 + c];
    }
    int row = row0 + r;
    if (row < NDST1)
        out[row * NOUT + c] = fmaxf(acc + b2[c], 0.0f);
    if (t < 16 && row0 + t < NDST1)
        out[NDST1 * NOUT + row0 + t] = (float)labels[row0 + t];
}

extern "C" void kernel_launch(void* const* d_in, const int* in_sizes, int n_in,
                              void* d_out, int out_size, void* d_ws, size_t ws_size,
                              hipStream_t stream) {
    const int*   user_word  = (const int*)d_in[0];
    const int*   labels     = (const int*)d_in[1];
    const int*   src0       = (const int*)d_in[2];
    const int*   dst0       = (const int*)d_in[3];
    const int*   src1       = (const int*)d_in[4];
    const int*   dst1       = (const int*)d_in[5];
    const float* word_table = (const float*)d_in[6];
    const float* W1         = (const float*)d_in[7];
    const float* b1         = (const float*)d_in[8];
    const float* W2         = (const float*)d_in[9];
    const float* b2         = (const float*)d_in[10];

    int* iws = (int*)d_ws;
    int* cnt0  = iws;            // 20000  ┐
    int* cnt1  = iws + 20000;    //  5000  │ zeroed (95000 ints)
    int* degO0 = iws + 25000;    // 50000  │
    int* degO1 = iws + 75000;    // 20000  ┘
    int* off0  = iws + 95000;    // 20001
    int* off1  = iws + 115001;   //  5001
    int* cur0  = iws + 120002;   // 20000
    int* cur1  = iws + 140002;   //  5000
    int* esrc0 = iws + 145002;   // 300000
    int* esrc1 = iws + 445002;   // 75000   (end 520002; pad to 520004)
    unsigned short* wtb   = (unsigned short*)(iws + 520004);    // 6.4M bf16
    unsigned short* x0b   = (unsigned short*)(iws + 3720004);   // 6.4M bf16
    unsigned short* h1b   = (unsigned short*)(iws + 6920004);   // 5.12M bf16
    unsigned short* agg1b = (unsigned short*)(iws + 9480004);   // 2.56M bf16
    unsigned short* agg2b = (unsigned short*)(iws + 10760004);  // 1.28M bf16 (end ≈ 45.6 MB)

    hipMemsetAsync(iws, 0, 95000 * sizeof(int), stream);

    prep_kernel<<<(NSRC0 * EMB / 8 + 255) / 256, 256, 0, stream>>>(
        word_table, wtb, src0, dst0, src1, dst1, cnt0, cnt1, degO0, degO1);
    scan_kernel<<<2, 1024, 0, stream>>>(cnt0, off0, cur0, cnt1, off1, cur1);
    bucket_kernel<<<(E0 + 255) / 256, 256, 0, stream>>>(src0, dst0, src1, dst1,
                                                        cur0, cur1, esrc0, esrc1);
    embed_kernel<<<NSRC0 / NPB, 256, 0, stream>>>(user_word, wtb, degO0, x0b);
    agg1_kernel<<<NDST0 / 4, 256, 0, stream>>>(off0, esrc0, x0b, agg1b);
    gemm1_kernel<<<NDST0 / 16, 256, 0, stream>>>(agg1b, degO1, W1, b1, h1b);
    agg2_kernel<<<NDST1 / 4, 256, 0, stream>>>(off1, esrc1, h1b, agg2b);
    gemm2_kernel<<<(NDST1 + 15) / 16, 256, 0, stream>>>(agg2b, W2, b2, labels, (float*)d_out);
}

// Round 11
// 344.108 us; speedup vs baseline: 1.0053x; 1.0053x over previous
//
#include <hip/hip_runtime.h>

#define E0     300000
#define E1     75000
#define NSRC0  50000
#define NDST0  20000
#define NDST1  5000
#define EMB    128
#define HID    256
#define NOUT   16

#define NPB        40     // nodes per embed block (1250 * 40 = 50000 exactly)
#define TILE_SHIFT 12     // 4096-row vocab tiles; tiles 0..12

// ---- bf16 helpers (RNE pack, cheap unpack) ----
__device__ __forceinline__ unsigned short f2bf(float f) {
    unsigned u = __float_as_uint(f);
    return (unsigned short)((u + 0x7FFFu + ((u >> 16) & 1u)) >> 16);
}
__device__ __forceinline__ float bflo(unsigned u) { return __uint_as_float(u << 16); }
__device__ __forceinline__ float bfhi(unsigned u) { return __uint_as_float(u & 0xFFFF0000u); }
__device__ __forceinline__ unsigned pack2(float a, float b) {
    return (unsigned)f2bf(a) | ((unsigned)f2bf(b) << 16);
}

// ---------------- prep: f32->bf16 table conv + degree histograms, fused ----------------
__global__ void prep_kernel(const float* __restrict__ wt, unsigned short* __restrict__ wtb,
                            const int* __restrict__ src0, const int* __restrict__ dst0,
                            const int* __restrict__ src1, const int* __restrict__ dst1,
                            int* cnt0, int* cnt1, int* degO0, int* degO1) {
    int i = blockIdx.x * blockDim.x + threadIdx.x;
    if (i < NSRC0 * EMB / 8) {            // 800000: pack 8 floats -> 8 bf16
        const float4* in = (const float4*)wt;
        float4 v0 = in[i * 2], v1 = in[i * 2 + 1];
        uint4 o;
        o.x = pack2(v0.x, v0.y); o.y = pack2(v0.z, v0.w);
        o.z = pack2(v1.x, v1.y); o.w = pack2(v1.z, v1.w);
        ((uint4*)wtb)[i] = o;
    }
    if (i < E0) {
        atomicAdd(&cnt0[dst0[i]], 1);
        atomicAdd(&degO0[src0[i]], 1);
    }
    if (i < E1) {
        atomicAdd(&cnt1[dst1[i]], 1);
        atomicAdd(&degO1[src1[i]], 1);
    }
}

// ---------------- exclusive scan (2 blocks x 1024 threads) ----------------
__device__ void scan_body(const int* __restrict__ cnt, int n,
                          int* __restrict__ off, int* __restrict__ cur) {
    __shared__ int sums[1024];
    int t = threadIdx.x;
    int chunk = (n + 1023) / 1024;
    int lo = t * chunk, hi = min(lo + chunk, n);
    int s = 0;
    for (int i = lo; i < hi; ++i) s += cnt[i];
    sums[t] = s;
    __syncthreads();
    for (int d = 1; d < 1024; d <<= 1) {
        int x = (t >= d) ? sums[t - d] : 0;
        __syncthreads();
        sums[t] += x;
        __syncthreads();
    }
    int run = (t == 0) ? 0 : sums[t - 1];
    for (int i = lo; i < hi; ++i) {
        off[i] = run; cur[i] = run;
        run += cnt[i];
    }
    if (t == 1023) off[n] = run;
}

__global__ void scan_kernel(const int* cnt0, int* off0, int* cur0,
                            const int* cnt1, int* off1, int* cur1) {
    if (blockIdx.x == 0) scan_body(cnt0, NDST0, off0, cur0);
    else                 scan_body(cnt1, NDST1, off1, cur1);
}

// ---------------- bucket edges by dst (build CSR adjacency) ----------------
__global__ void bucket_kernel(const int* __restrict__ src0, const int* __restrict__ dst0,
                              const int* __restrict__ src1, const int* __restrict__ dst1,
                              int* cur0, int* cur1, int* esrc0, int* esrc1) {
    int i = blockIdx.x * blockDim.x + threadIdx.x;
    if (i < E0) {
        int p = atomicAdd(&cur0[dst0[i]], 1);
        esrc0[p] = src0[i];
    }
    if (i < E1) {
        int p = atomicAdd(&cur1[dst1[i]], 1);
        esrc1[p] = src1[i];
    }
}

// ---------------- fused embedding mean: LDS tile-sort + bf16 gather, 4-deep MLP -------
__global__ void embed_kernel(const int* __restrict__ user_word,
                             const unsigned short* __restrict__ wtb,
                             const int* __restrict__ degO0,
                             unsigned short* __restrict__ x0b) {
    __shared__ int raw[NPB * 50];
    __shared__ int srt[NPB * 50];
    __shared__ int cnt[NPB * 17];        // stride 17: avoids LDS bank conflicts
    int t = threadIdx.x;
    int base = blockIdx.x * NPB * 50;
    for (int j = t; j < NPB * 50; j += 256)
        raw[j] = user_word[base + j];
    for (int j = t; j < NPB * 17; j += 256)
        cnt[j] = 0;
    __syncthreads();
    if (t < NPB) {                                // 1 thread sorts 1 node (in LDS)
        int* c = cnt + t * 17;
        const int* r = raw + t * 50;
        for (int j = 0; j < 50; ++j) c[r[j] >> TILE_SHIFT]++;
        int run = 0;
        for (int b = 0; b < 13; ++b) { int v = c[b]; c[b] = run; run += v; }
        int* o = srt + t * 50;
        for (int j = 0; j < 50; ++j) { int v = r[j]; o[c[v >> TILE_SHIFT]++] = v; }
    }
    __syncthreads();
    int g = t >> 5, l = t & 31;                   // 8 groups of 32 lanes
    const uint2* wt2 = (const uint2*)wtb;         // row = 32 uint2
    for (int n = g; n < NPB; n += 8) {            // 5 nodes per group
        const int* id = srt + n * 50;
        float a0 = 0.f, a1 = 0.f, a2 = 0.f, a3 = 0.f;
        #pragma unroll 3
        for (int j = 0; j < 48; j += 4) {         // 4 loads in flight
            uint2 v0 = wt2[id[j] * 32 + l];
            uint2 v1 = wt2[id[j + 1] * 32 + l];
            uint2 v2 = wt2[id[j + 2] * 32 + l];
            uint2 v3 = wt2[id[j + 3] * 32 + l];
            a0 += bflo(v0.x) + bflo(v1.x) + bflo(v2.x) + bflo(v3.x);
            a1 += bfhi(v0.x) + bfhi(v1.x) + bfhi(v2.x) + bfhi(v3.x);
            a2 += bflo(v0.y) + bflo(v1.y) + bflo(v2.y) + bflo(v3.y);
            a3 += bfhi(v0.y) + bfhi(v1.y) + bfhi(v2.y) + bfhi(v3.y);
        }
        {                                         // remainder j = 48, 49
            uint2 v0 = wt2[id[48] * 32 + l];
            uint2 v1 = wt2[id[49] * 32 + l];
            a0 += bflo(v0.x) + bflo(v1.x); a1 += bfhi(v0.x) + bfhi(v1.x);
            a2 += bflo(v0.y) + bflo(v1.y); a3 += bfhi(v0.y) + bfhi(v1.y);
        }
        int node = blockIdx.x * NPB + n;
        float s = rsqrtf(fmaxf((float)degO0[node], 1.0f)) * 0.02f;  // 1/50 mean
        uint2 o2; o2.x = pack2(a0 * s, a1 * s); o2.y = pack2(a2 * s, a3 * s);
        ((uint2*)x0b)[node * 32 + l] = o2;
    }
}

// ---------------- layer-1 gather-aggregate (bf16 in/out, 1 wave/dst, 2-deep MLP) -----
__global__ void agg1_kernel(const int* __restrict__ off0, const int* __restrict__ esrc0,
                            const unsigned short* __restrict__ x0b,
                            unsigned short* __restrict__ agg1b) {
    int d = blockIdx.x;
    int t = threadIdx.x;               // 0..63
    int half = t >> 5, l = t & 31;
    int lo = off0[d], hi = off0[d + 1];
    const uint2* x2 = (const uint2*)x0b;           // row = 32 uint2
    float a0 = 0.f, a1 = 0.f, a2 = 0.f, a3 = 0.f;
    int j = lo + half;
    for (; j + 2 < hi; j += 4) {                   // 2 loads in flight per half
        uint2 va = x2[esrc0[j] * 32 + l];
        uint2 vb = x2[esrc0[j + 2] * 32 + l];
        a0 += bflo(va.x) + bflo(vb.x); a1 += bfhi(va.x) + bfhi(vb.x);
        a2 += bflo(va.y) + bflo(vb.y); a3 += bfhi(va.y) + bfhi(vb.y);
    }
    if (j < hi) {
        uint2 v = x2[esrc0[j] * 32 + l];
        a0 += bflo(v.x); a1 += bfhi(v.x); a2 += bflo(v.y); a3 += bfhi(v.y);
    }
    a0 += __shfl_down(a0, 32); a1 += __shfl_down(a1, 32);
    a2 += __shfl_down(a2, 32); a3 += __shfl_down(a3, 32);
    if (half == 0) {
        float sc = rsqrtf(fmaxf((float)(hi - lo), 1.0f));
        uint2 o; o.x = pack2(a0 * sc, a1 * sc); o.y = pack2(a2 * sc, a3 * sc);
        ((uint2*)agg1b)[d * 32 + l] = o;
    }
}

// ---------------- GEMM1: h1 = relu(agg1 @ W1 + b1) * rsqrt(deg_out1), bf16 out ------
__global__ void gemm1_kernel(const unsigned short* __restrict__ agg1b,
                             const int* __restrict__ degO1,
                             const float* __restrict__ W1, const float* __restrict__ b1,
                             unsigned short* __restrict__ h1b) {
    __shared__ float A[16 * 132];     // pad 132 (%4==0: aligned float4 rows)
    __shared__ float s_out[16];
    int t = threadIdx.x;
    int row0 = blockIdx.x * 16;
    if (t < 16) s_out[t] = rsqrtf(fmaxf((float)degO1[row0 + t], 1.0f));
    const unsigned* ag = (const unsigned*)agg1b + row0 * 64;   // 16 rows x 64 uint
    for (int j = t; j < 16 * 64; j += 256) {
        unsigned v = ag[j];
        int r = j >> 6, p = j & 63;
        A[r * 132 + 2 * p]     = bflo(v);
        A[r * 132 + 2 * p + 1] = bfhi(v);
    }
    __syncthreads();
    float acc[16];
    #pragma unroll
    for (int r = 0; r < 16; ++r) acc[r] = 0.f;
    for (int k4 = 0; k4 < 32; ++k4) {
        float w0 = W1[(k4 * 4 + 0) * 256 + t];     // coalesced across t
        float w1 = W1[(k4 * 4 + 1) * 256 + t];
        float w2 = W1[(k4 * 4 + 2) * 256 + t];
        float w3 = W1[(k4 * 4 + 3) * 256 + t];
        #pragma unroll
        for (int r = 0; r < 16; ++r) {
            float4 a = *(const float4*)(A + r * 132 + k4 * 4);  // b128 broadcast
            acc[r] += a.x * w0 + a.y * w1 + a.z * w2 + a.w * w3;
        }
    }
    float bb = b1[t];
    #pragma unroll
    for (int r = 0; r < 16; ++r)
        h1b[(row0 + r) * 256 + t] = f2bf(fmaxf(acc[r] + bb, 0.f) * s_out[r]);
}

// ---------------- layer-2 gather-aggregate (bf16 in/out, 1 wave/dst) -----------
__global__ void agg2_kernel(const int* __restrict__ off1, const int* __restrict__ esrc1,
                            const unsigned short* __restrict__ h1b,
                            unsigned short* __restrict__ agg2b) {
    int d = blockIdx.x;
    int l = threadIdx.x;               // 0..63
    int lo = off1[d], hi = off1[d + 1];
    const uint2* h2 = (const uint2*)h1b;           // row = 64 uint2
    float a0 = 0.f, a1 = 0.f, a2 = 0.f, a3 = 0.f;
    int j = lo;
    for (; j + 1 < hi; j += 2) {
        uint2 v0 = h2[esrc1[j] * 64 + l];
        uint2 v1 = h2[esrc1[j + 1] * 64 + l];
        a0 += bflo(v0.x) + bflo(v1.x); a1 += bfhi(v0.x) + bfhi(v1.x);
        a2 += bflo(v0.y) + bflo(v1.y); a3 += bfhi(v0.y) + bfhi(v1.y);
    }
    if (j < hi) {
        uint2 v = h2[esrc1[j] * 64 + l];
        a0 += bflo(v.x); a1 += bfhi(v.x); a2 += bflo(v.y); a3 += bfhi(v.y);
    }
    float sc = rsqrtf(fmaxf((float)(hi - lo), 1.0f));
    uint2 o; o.x = pack2(a0 * sc, a1 * sc); o.y = pack2(a2 * sc, a3 * sc);
    ((uint2*)agg2b)[d * 64 + l] = o;
}

// ---------------- GEMM2: out = relu(agg2 @ W2 + b2)  (+ labels passthrough) ----------
__global__ void gemm2_kernel(const unsigned short* __restrict__ agg2b,
                             const float* __restrict__ W2, const float* __restrict__ b2,
                             const int* __restrict__ labels,
                             float* __restrict__ out) {
    __shared__ float A[16 * 260];     // pad 260 (%4==0, breaks 16-way bank stride)
    __shared__ float Wl[256 * 16];
    int t = threadIdx.x;
    int row0 = blockIdx.x * 16;
    for (int j = t; j < 256 * 16; j += 256) Wl[j] = W2[j];
    const unsigned* ag = (const unsigned*)agg2b + row0 * 128;  // 16 rows x 128 uint
    for (int j = t; j < 16 * 128; j += 256) {
        int r = j >> 7, p = j & 127;
        unsigned v = (row0 + r < NDST1) ? ag[j] : 0u;
        A[r * 260 + 2 * p]     = bflo(v);
        A[r * 260 + 2 * p + 1] = bfhi(v);
    }
    __syncthreads();
    int r = t >> 4, c = t & 15;
    float acc = 0.0f;
    for (int k4 = 0; k4 < 64; ++k4) {
        float4 a = *(const float4*)(A + r * 260 + k4 * 4);     // b128
        acc += a.x * Wl[(k4 * 4 + 0) * 16 + c] + a.y * Wl[(k4 * 4 + 1) * 16 + c]
             + a.z * Wl[(k4 * 4 + 2) * 16 + c] + a.w * Wl[(k4 * 4 + 3) * 16 + c];
    }
    int row = row0 + r;
    if (row < NDST1)
        out[row * NOUT + c] = fmaxf(acc + b2[c], 0.0f);
    if (t < 16 && row0 + t < NDST1)
        out[NDST1 * NOUT + row0 + t] = (float)labels[row0 + t];
}

extern "C" void kernel_launch(void* const* d_in, const int* in_sizes, int n_in,
                              void* d_out, int out_size, void* d_ws, size_t ws_size,
                              hipStream_t stream) {
    const int*   user_word  = (const int*)d_in[0];
    const int*   labels     = (const int*)d_in[1];
    const int*   src0       = (const int*)d_in[2];
    const int*   dst0       = (const int*)d_in[3];
    const int*   src1       = (const int*)d_in[4];
    const int*   dst1       = (const int*)d_in[5];
    const float* word_table = (const float*)d_in[6];
    const float* W1         = (const float*)d_in[7];
    const float* b1         = (const float*)d_in[8];
    const float* W2         = (const float*)d_in[9];
    const float* b2         = (const float*)d_in[10];

    int* iws = (int*)d_ws;
    int* cnt0  = iws;            // 20000  ┐
    int* cnt1  = iws + 20000;    //  5000  │ zeroed (95000 ints)
    int* degO0 = iws + 25000;    // 50000  │
    int* degO1 = iws + 75000;    // 20000  ┘
    int* off0  = iws + 95000;    // 20001
    int* off1  = iws + 115001;   //  5001
    int* cur0  = iws + 120002;   // 20000
    int* cur1  = iws + 140002;   //  5000
    int* esrc0 = iws + 145002;   // 300000
    int* esrc1 = iws + 445002;   // 75000   (end 520002; pad to 520004)
    unsigned short* wtb   = (unsigned short*)(iws + 520004);    // 6.4M bf16
    unsigned short* x0b   = (unsigned short*)(iws + 3720004);   // 6.4M bf16
    unsigned short* h1b   = (unsigned short*)(iws + 6920004);   // 5.12M bf16
    unsigned short* agg1b = (unsigned short*)(iws + 9480004);   // 2.56M bf16
    unsigned short* agg2b = (unsigned short*)(iws + 10760004);  // 1.28M bf16 (end ≈ 45.6 MB)

    hipMemsetAsync(iws, 0, 95000 * sizeof(int), stream);

    prep_kernel<<<(NSRC0 * EMB / 8 + 255) / 256, 256, 0, stream>>>(
        word_table, wtb, src0, dst0, src1, dst1, cnt0, cnt1, degO0, degO1);
    scan_kernel<<<2, 1024, 0, stream>>>(cnt0, off0, cur0, cnt1, off1, cur1);
    bucket_kernel<<<(E0 + 255) / 256, 256, 0, stream>>>(src0, dst0, src1, dst1,
                                                        cur0, cur1, esrc0, esrc1);
    embed_kernel<<<NSRC0 / NPB, 256, 0, stream>>>(user_word, wtb, degO0, x0b);
    agg1_kernel<<<NDST0, 64, 0, stream>>>(off0, esrc0, x0b, agg1b);
    gemm1_kernel<<<NDST0 / 16, 256, 0, stream>>>(agg1b, degO1, W1, b1, h1b);
    agg2_kernel<<<NDST1, 64, 0, stream>>>(off1, esrc1, h1b, agg2b);
    gemm2_kernel<<<(NDST1 + 15) / 16, 256, 0, stream>>>(agg2b, W2, b2, labels, (float*)d_out);
}

// Round 12
// 309.978 us; speedup vs baseline: 1.1160x; 1.1101x over previous
//
#include <hip/hip_runtime.h>

#define E0     300000
#define E1     75000
#define NSRC0  50000
#define NDST0  20000
#define NDST1  5000
#define EMB    128
#define HID    256
#define NOUT   16

#define NPB        40     // nodes per embed block (1250 * 40 = 50000 exactly)
#define TILE_SHIFT 12     // 4096-row vocab tiles; tiles 0..12
#define NEMB_BLK   (NSRC0 / NPB)   // 1250

typedef __attribute__((ext_vector_type(8))) short bf16x8;   // MFMA A/B frag (4 VGPRs)
typedef __attribute__((ext_vector_type(4))) float f32x4;    // MFMA C/D frag

// ---- bf16 helpers (RNE pack, cheap unpack) ----
__device__ __forceinline__ unsigned short f2bf(float f) {
    unsigned u = __float_as_uint(f);
    return (unsigned short)((u + 0x7FFFu + ((u >> 16) & 1u)) >> 16);
}
__device__ __forceinline__ float bflo(unsigned u) { return __uint_as_float(u << 16); }
__device__ __forceinline__ float bfhi(unsigned u) { return __uint_as_float(u & 0xFFFF0000u); }
__device__ __forceinline__ unsigned pack2(float a, float b) {
    return (unsigned)f2bf(a) | ((unsigned)f2bf(b) << 16);
}

// ---------------- prep: table->bf16, W1^T/W2^T->bf16, degree histograms ----------------
__global__ void prep_kernel(const float* __restrict__ wt, unsigned short* __restrict__ wtb,
                            const float* __restrict__ W1, unsigned short* __restrict__ W1Tb,
                            const float* __restrict__ W2, unsigned short* __restrict__ W2Tb,
                            const int* __restrict__ src0, const int* __restrict__ dst0,
                            const int* __restrict__ src1, const int* __restrict__ dst1,
                            int* cnt0, int* cnt1, int* degO0, int* degO1) {
    int i = blockIdx.x * blockDim.x + threadIdx.x;
    if (i < NSRC0 * EMB / 8) {            // 800000: pack 8 floats -> 8 bf16
        const float4* in = (const float4*)wt;
        float4 v0 = in[i * 2], v1 = in[i * 2 + 1];
        uint4 o;
        o.x = pack2(v0.x, v0.y); o.y = pack2(v0.z, v0.w);
        o.z = pack2(v1.x, v1.y); o.w = pack2(v1.z, v1.w);
        ((uint4*)wtb)[i] = o;
    }
    if (i < EMB * HID) {                  // W1[128][256] -> W1T bf16 [256][128]
        int n = i & 255, k = i >> 8;      // coalesced read W1[k*256+n]
        W1Tb[n * 128 + k] = f2bf(W1[i]);
    }
    if (i < HID * NOUT) {                 // W2[256][16] -> W2T bf16 [16][256]
        int n = i & 15, k = i >> 4;       // coalesced read W2[k*16+n]
        W2Tb[n * 256 + k] = f2bf(W2[i]);
    }
    if (i < E0) {
        atomicAdd(&cnt0[dst0[i]], 1);
        atomicAdd(&degO0[src0[i]], 1);
    }
    if (i < E1) {
        atomicAdd(&cnt1[dst1[i]], 1);
        atomicAdd(&degO1[src1[i]], 1);
    }
}

// ---------------- exclusive scan body (256 threads) ----------------
__device__ void scan_body(const int* __restrict__ cnt, int n,
                          int* __restrict__ off, int* __restrict__ cur) {
    __shared__ int sums[256];
    int t = threadIdx.x;
    int chunk = (n + 255) / 256;
    int lo = t * chunk, hi = min(lo + chunk, n);
    int s = 0;
    for (int i = lo; i < hi; ++i) s += cnt[i];
    sums[t] = s;
    __syncthreads();
    for (int d = 1; d < 256; d <<= 1) {
        int x = (t >= d) ? sums[t - d] : 0;
        __syncthreads();
        sums[t] += x;
        __syncthreads();
    }
    int run = (t == 0) ? 0 : sums[t - 1];
    for (int i = lo; i < hi; ++i) {
        off[i] = run; cur[i] = run;
        run += cnt[i];
    }
    if (t == 255) off[n] = run;
}

// ---------------- bucket edges by dst (build CSR adjacency) ----------------
__global__ void bucket_kernel(const int* __restrict__ src0, const int* __restrict__ dst0,
                              const int* __restrict__ src1, const int* __restrict__ dst1,
                              int* cur0, int* cur1, int* esrc0, int* esrc1) {
    int i = blockIdx.x * blockDim.x + threadIdx.x;
    if (i < E0) {
        int p = atomicAdd(&cur0[dst0[i]], 1);
        esrc0[p] = src0[i];
    }
    if (i < E1) {
        int p = atomicAdd(&cur1[dst1[i]], 1);
        esrc1[p] = src1[i];
    }
}

// ---------------- embed (blocks 0..1249) + both scans (blocks 1250,1251) fused -------
// Scans (latency-bound, 2 blocks) hide under the latency-bound embed gather.
__global__ void embed_scan_kernel(const int* __restrict__ user_word,
                                  const unsigned short* __restrict__ wtb,
                                  const int* __restrict__ degO0,
                                  unsigned short* __restrict__ x0b,
                                  const int* cnt0, int* off0, int* cur0,
                                  const int* cnt1, int* off1, int* cur1) {
    if (blockIdx.x >= NEMB_BLK) {
        if (blockIdx.x == NEMB_BLK) scan_body(cnt0, NDST0, off0, cur0);
        else                        scan_body(cnt1, NDST1, off1, cur1);
        return;
    }
    __shared__ int raw[NPB * 50];
    __shared__ int srt[NPB * 50];
    __shared__ int cnt[NPB * 17];        // stride 17: avoids LDS bank conflicts
    int t = threadIdx.x;
    int base = blockIdx.x * NPB * 50;
    for (int j = t; j < NPB * 50; j += 256)
        raw[j] = user_word[base + j];
    for (int j = t; j < NPB * 17; j += 256)
        cnt[j] = 0;
    __syncthreads();
    if (t < NPB) {                                // 1 thread sorts 1 node (in LDS)
        int* c = cnt + t * 17;
        const int* r = raw + t * 50;
        for (int j = 0; j < 50; ++j) c[r[j] >> TILE_SHIFT]++;
        int run = 0;
        for (int b = 0; b < 13; ++b) { int v = c[b]; c[b] = run; run += v; }
        int* o = srt + t * 50;
        for (int j = 0; j < 50; ++j) { int v = r[j]; o[c[v >> TILE_SHIFT]++] = v; }
    }
    __syncthreads();
    int g = t >> 5, l = t & 31;                   // 8 groups of 32 lanes
    const uint2* wt2 = (const uint2*)wtb;         // row = 32 uint2
    for (int n = g; n < NPB; n += 8) {            // 5 nodes per group
        const int* id = srt + n * 50;
        float a0 = 0.f, a1 = 0.f, a2 = 0.f, a3 = 0.f;
        #pragma unroll 2
        for (int j = 0; j < 50; j += 2) {         // 2 loads in flight
            uint2 v0 = wt2[id[j] * 32 + l];
            uint2 v1 = wt2[id[j + 1] * 32 + l];
            a0 += bflo(v0.x) + bflo(v1.x); a1 += bfhi(v0.x) + bfhi(v1.x);
            a2 += bflo(v0.y) + bflo(v1.y); a3 += bfhi(v0.y) + bfhi(v1.y);
        }
        int node = blockIdx.x * NPB + n;
        float s = rsqrtf(fmaxf((float)degO0[node], 1.0f)) * 0.02f;  // 1/50 mean
        uint2 o2; o2.x = pack2(a0 * s, a1 * s); o2.y = pack2(a2 * s, a3 * s);
        ((uint2*)x0b)[node * 32 + l] = o2;
    }
}

// ---------------- layer-1 gather-aggregate (bf16 in/out, 1 wave/dst) ----------
__global__ void agg1_kernel(const int* __restrict__ off0, const int* __restrict__ esrc0,
                            const unsigned short* __restrict__ x0b,
                            unsigned short* __restrict__ agg1b) {
    int d = blockIdx.x;
    int t = threadIdx.x;               // 0..63
    int half = t >> 5, l = t & 31;
    int lo = off0[d], hi = off0[d + 1];
    const uint2* x2 = (const uint2*)x0b;           // row = 32 uint2
    float a0 = 0.f, a1 = 0.f, a2 = 0.f, a3 = 0.f;
    for (int j = lo + half; j < hi; j += 2) {
        uint2 v = x2[esrc0[j] * 32 + l];
        a0 += bflo(v.x); a1 += bfhi(v.x); a2 += bflo(v.y); a3 += bfhi(v.y);
    }
    a0 += __shfl_down(a0, 32); a1 += __shfl_down(a1, 32);
    a2 += __shfl_down(a2, 32); a3 += __shfl_down(a3, 32);
    if (half == 0) {
        float sc = rsqrtf(fmaxf((float)(hi - lo), 1.0f));
        uint2 o; o.x = pack2(a0 * sc, a1 * sc); o.y = pack2(a2 * sc, a3 * sc);
        ((uint2*)agg1b)[d * 32 + l] = o;
    }
}

// ---------------- GEMM1 via MFMA: h1 = relu(agg1 @ W1 + b1) * rsqrt(deg_out1) --------
// Block = 256 thr = 4 waves; 16 rows x 256 cols. Wave w covers col-tiles 4w..4w+3.
// A-frag A[m=lane&15][k=quad*8+j] straight from global agg1b (bf16, row-major 128).
// B-frag = W1T[n=lane&15][k contiguous]. C/D: col=lane&15, row=quad*4+reg.
__global__ void gemm1_kernel(const unsigned short* __restrict__ agg1b,
                             const int* __restrict__ degO1,
                             const unsigned short* __restrict__ W1Tb,
                             const float* __restrict__ b1,
                             unsigned short* __restrict__ h1b) {
    __shared__ float s_out[16];
    int t = threadIdx.x;
    int row0 = blockIdx.x * 16;
    if (t < 16) s_out[t] = rsqrtf(fmaxf((float)degO1[row0 + t], 1.0f));
    __syncthreads();
    int w = t >> 6, lane = t & 63;
    int m = lane & 15, quad = lane >> 4;
    const unsigned short* abase = agg1b + (row0 + m) * 128 + quad * 8;
    bf16x8 afr[4];
    #pragma unroll
    for (int ks = 0; ks < 4; ++ks)
        afr[ks] = *(const bf16x8*)(abase + ks * 32);
    #pragma unroll
    for (int ct = 0; ct < 4; ++ct) {
        int gcol0 = (w * 4 + ct) * 16;
        const unsigned short* bbase = W1Tb + (gcol0 + m) * 128 + quad * 8;
        f32x4 acc = {0.f, 0.f, 0.f, 0.f};
        #pragma unroll
        for (int ks = 0; ks < 4; ++ks) {
            bf16x8 bfr = *(const bf16x8*)(bbase + ks * 32);
            acc = __builtin_amdgcn_mfma_f32_16x16x32_bf16(afr[ks], bfr, acc, 0, 0, 0);
        }
        int gcol = gcol0 + m;
        float bb = b1[gcol];
        #pragma unroll
        for (int reg = 0; reg < 4; ++reg) {
            int row = quad * 4 + reg;
            h1b[(row0 + row) * 256 + gcol] = f2bf(fmaxf(acc[reg] + bb, 0.f) * s_out[row]);
        }
    }
}

// ---------------- layer-2 gather-aggregate (bf16 in/out, 1 wave/dst) -----------
__global__ void agg2_kernel(const int* __restrict__ off1, const int* __restrict__ esrc1,
                            const unsigned short* __restrict__ h1b,
                            unsigned short* __restrict__ agg2b) {
    int d = blockIdx.x;
    int l = threadIdx.x;               // 0..63
    int lo = off1[d], hi = off1[d + 1];
    const uint2* h2 = (const uint2*)h1b;           // row = 64 uint2
    float a0 = 0.f, a1 = 0.f, a2 = 0.f, a3 = 0.f;
    int j = lo;
    for (; j + 1 < hi; j += 2) {
        uint2 v0 = h2[esrc1[j] * 64 + l];
        uint2 v1 = h2[esrc1[j + 1] * 64 + l];
        a0 += bflo(v0.x) + bflo(v1.x); a1 += bfhi(v0.x) + bfhi(v1.x);
        a2 += bflo(v0.y) + bflo(v1.y); a3 += bfhi(v0.y) + bfhi(v1.y);
    }
    if (j < hi) {
        uint2 v = h2[esrc1[j] * 64 + l];
        a0 += bflo(v.x); a1 += bfhi(v.x); a2 += bflo(v.y); a3 += bfhi(v.y);
    }
    float sc = rsqrtf(fmaxf((float)(hi - lo), 1.0f));
    uint2 o; o.x = pack2(a0 * sc, a1 * sc); o.y = pack2(a2 * sc, a3 * sc);
    ((uint2*)agg2b)[d * 64 + l] = o;
}

// ---------------- GEMM2 via MFMA: out = relu(agg2 @ W2 + b2) (+ labels) --------------
// 1 wave per 16 rows; K=256 -> 8 MFMA. Out cols = 16 = one tile.
__global__ void gemm2_kernel(const unsigned short* __restrict__ agg2b,
                             const unsigned short* __restrict__ W2Tb,
                             const float* __restrict__ b2,
                             const int* __restrict__ labels,
                             float* __restrict__ out) {
    int lane = threadIdx.x;            // 0..63
    int row0 = blockIdx.x * 16;
    int m = lane & 15, quad = lane >> 4;
    int arow = min(row0 + m, NDST1 - 1);           // clamp OOB reads (last block)
    const unsigned short* abase = agg2b + arow * 256 + quad * 8;
    const unsigned short* bbase = W2Tb + m * 256 + quad * 8;
    f32x4 acc = {0.f, 0.f, 0.f, 0.f};
    #pragma unroll
    for (int ks = 0; ks < 8; ++ks) {
        bf16x8 af = *(const bf16x8*)(abase + ks * 32);
        bf16x8 bf = *(const bf16x8*)(bbase + ks * 32);
        acc = __builtin_amdgcn_mfma_f32_16x16x32_bf16(af, bf, acc, 0, 0, 0);
    }
    float bb = b2[m];
    #pragma unroll
    for (int reg = 0; reg < 4; ++reg) {
        int row = row0 + quad * 4 + reg;
        if (row < NDST1)
            out[row * NOUT + m] = fmaxf(acc[reg] + bb, 0.f);
    }
    if (lane < 16 && row0 + lane < NDST1)
        out[NDST1 * NOUT + row0 + lane] = (float)labels[row0 + lane];
}

extern "C" void kernel_launch(void* const* d_in, const int* in_sizes, int n_in,
                              void* d_out, int out_size, void* d_ws, size_t ws_size,
                              hipStream_t stream) {
    const int*   user_word  = (const int*)d_in[0];
    const int*   labels     = (const int*)d_in[1];
    const int*   src0       = (const int*)d_in[2];
    const int*   dst0       = (const int*)d_in[3];
    const int*   src1       = (const int*)d_in[4];
    const int*   dst1       = (const int*)d_in[5];
    const float* word_table = (const float*)d_in[6];
    const float* W1         = (const float*)d_in[7];
    const float* b1         = (const float*)d_in[8];
    const float* W2         = (const float*)d_in[9];
    const float* b2         = (const float*)d_in[10];

    int* iws = (int*)d_ws;
    int* cnt0  = iws;            // 20000  ┐
    int* cnt1  = iws + 20000;    //  5000  │ zeroed (95000 ints)
    int* degO0 = iws + 25000;    // 50000  │
    int* degO1 = iws + 75000;    // 20000  ┘
    int* off0  = iws + 95000;    // 20001
    int* off1  = iws + 115001;   //  5001
    int* cur0  = iws + 120002;   // 20000
    int* cur1  = iws + 140002;   //  5000
    int* esrc0 = iws + 145002;   // 300000
    int* esrc1 = iws + 445002;   // 75000   (end 520002; pad to 520004)
    unsigned short* wtb   = (unsigned short*)(iws + 520004);    // 6.4M bf16
    unsigned short* x0b   = (unsigned short*)(iws + 3720004);   // 6.4M bf16
    unsigned short* h1b   = (unsigned short*)(iws + 6920004);   // 5.12M bf16
    unsigned short* agg1b = (unsigned short*)(iws + 9480004);   // 2.56M bf16
    unsigned short* agg2b = (unsigned short*)(iws + 10760004);  // 1.28M bf16
    unsigned short* W1Tb  = (unsigned short*)(iws + 11400004);  // 32768 bf16
    unsigned short* W2Tb  = (unsigned short*)(iws + 11416388);  // 4096 bf16 (end ≈ 45.7 MB)

    hipMemsetAsync(iws, 0, 95000 * sizeof(int), stream);

    prep_kernel<<<(NSRC0 * EMB / 8 + 255) / 256, 256, 0, stream>>>(
        word_table, wtb, W1, W1Tb, W2, W2Tb,
        src0, dst0, src1, dst1, cnt0, cnt1, degO0, degO1);
    embed_scan_kernel<<<NEMB_BLK + 2, 256, 0, stream>>>(
        user_word, wtb, degO0, x0b, cnt0, off0, cur0, cnt1, off1, cur1);
    bucket_kernel<<<(E0 + 255) / 256, 256, 0, stream>>>(src0, dst0, src1, dst1,
                                                        cur0, cur1, esrc0, esrc1);
    agg1_kernel<<<NDST0, 64, 0, stream>>>(off0, esrc0, x0b, agg1b);
    gemm1_kernel<<<NDST0 / 16, 256, 0, stream>>>(agg1b, degO1, W1Tb, b1, h1b);
    agg2_kernel<<<NDST1, 64, 0, stream>>>(off1, esrc1, h1b, agg2b);
    gemm2_kernel<<<(NDST1 + 15) / 16, 64, 0, stream>>>(agg2b, W2Tb, b2, labels, (float*)d_out);
}

// Round 13
// 285.928 us; speedup vs baseline: 1.2098x; 1.0841x over previous
//
#include <hip/hip_runtime.h>

#define E0     300000
#define E1     75000
#define NSRC0  50000
#define NDST0  20000
#define NDST1  5000
#define EMB    128
#define HID    256
#define NOUT   16

#define NPB        40     // nodes per embed block (1250 * 40 = 50000 exactly)
#define TILE_SHIFT 12     // 4096-row vocab tiles; tiles 0..12

#define X0S  32.0f        // fp8 pre-scale for x0  (undone in agg1)
#define H1S  64.0f        // fp8 pre-scale for h1  (undone in agg2)

typedef __attribute__((ext_vector_type(8))) short bf16x8;   // MFMA A/B frag (4 VGPRs)
typedef __attribute__((ext_vector_type(4))) float f32x4;    // MFMA C/D frag

// ---- bf16 helpers ----
__device__ __forceinline__ unsigned short f2bf(float f) {
    unsigned u = __float_as_uint(f);
    return (unsigned short)((u + 0x7FFFu + ((u >> 16) & 1u)) >> 16);
}
__device__ __forceinline__ float bflo(unsigned u) { return __uint_as_float(u << 16); }
__device__ __forceinline__ float bfhi(unsigned u) { return __uint_as_float(u & 0xFFFF0000u); }
__device__ __forceinline__ unsigned pack2(float a, float b) {
    return (unsigned)f2bf(a) | ((unsigned)f2bf(b) << 16);
}
// ---- fp8 e4m3 helpers (HW cvt) ----
__device__ __forceinline__ unsigned pack4_fp8(float a0, float a1, float a2, float a3) {
    unsigned p = 0;
    p = __builtin_amdgcn_cvt_pk_fp8_f32(a0, a1, p, false);   // bytes 0,1
    p = __builtin_amdgcn_cvt_pk_fp8_f32(a2, a3, p, true);    // bytes 2,3
    return p;
}
__device__ __forceinline__ unsigned char f2fp8(float v) {
    unsigned p = __builtin_amdgcn_cvt_pk_fp8_f32(v, v, 0, false);
    return (unsigned char)(p & 0xFF);
}

// ---------------- prep: table->fp8, W1^T/W2^T->bf16, degree histograms ----------------
__global__ void prep_kernel(const float* __restrict__ wt, unsigned char* __restrict__ wt8,
                            const float* __restrict__ W1, unsigned short* __restrict__ W1Tb,
                            const float* __restrict__ W2, unsigned short* __restrict__ W2Tb,
                            const int* __restrict__ src0, const int* __restrict__ dst0,
                            const int* __restrict__ src1, const int* __restrict__ dst1,
                            int* cnt0, int* cnt1, int* degO0, int* degO1) {
    int i = blockIdx.x * blockDim.x + threadIdx.x;
    if (i < NSRC0 * EMB / 8) {            // 800000: pack 8 floats -> 8 fp8
        const float4* in = (const float4*)wt;
        float4 v0 = in[i * 2], v1 = in[i * 2 + 1];
        uint2 o;
        o.x = pack4_fp8(v0.x, v0.y, v0.z, v0.w);
        o.y = pack4_fp8(v1.x, v1.y, v1.z, v1.w);
        ((uint2*)wt8)[i] = o;
    }
    if (i < EMB * HID) {                  // W1[128][256] -> W1T bf16 [256][128]
        int n = i & 255, k = i >> 8;
        W1Tb[n * 128 + k] = f2bf(W1[i]);
    }
    if (i < HID * NOUT) {                 // W2[256][16] -> W2T bf16 [16][256]
        int n = i & 15, k = i >> 4;
        W2Tb[n * 256 + k] = f2bf(W2[i]);
    }
    if (i < E0) {
        atomicAdd(&cnt0[dst0[i]], 1);
        atomicAdd(&degO0[src0[i]], 1);
    }
    if (i < E1) {
        atomicAdd(&cnt1[dst1[i]], 1);
        atomicAdd(&degO1[src1[i]], 1);
    }
}

// ---------------- exclusive scan (2 blocks x 1024 threads, own dispatch) --------------
__device__ void scan_body(const int* __restrict__ cnt, int n,
                          int* __restrict__ off, int* __restrict__ cur) {
    __shared__ int sums[1024];
    int t = threadIdx.x;
    int chunk = (n + 1023) / 1024;
    int lo = t * chunk, hi = min(lo + chunk, n);
    int s = 0;
    for (int i = lo; i < hi; ++i) s += cnt[i];
    sums[t] = s;
    __syncthreads();
    for (int d = 1; d < 1024; d <<= 1) {
        int x = (t >= d) ? sums[t - d] : 0;
        __syncthreads();
        sums[t] += x;
        __syncthreads();
    }
    int run = (t == 0) ? 0 : sums[t - 1];
    for (int i = lo; i < hi; ++i) {
        off[i] = run; cur[i] = run;
        run += cnt[i];
    }
    if (t == 1023) off[n] = run;
}

__global__ void scan_kernel(const int* cnt0, int* off0, int* cur0,
                            const int* cnt1, int* off1, int* cur1) {
    if (blockIdx.x == 0) scan_body(cnt0, NDST0, off0, cur0);
    else                 scan_body(cnt1, NDST1, off1, cur1);
}

// ---------------- bucket edges by dst (build CSR adjacency) ----------------
__global__ void bucket_kernel(const int* __restrict__ src0, const int* __restrict__ dst0,
                              const int* __restrict__ src1, const int* __restrict__ dst1,
                              int* cur0, int* cur1, int* esrc0, int* esrc1) {
    int i = blockIdx.x * blockDim.x + threadIdx.x;
    if (i < E0) {
        int p = atomicAdd(&cur0[dst0[i]], 1);
        esrc0[p] = src0[i];
    }
    if (i < E1) {
        int p = atomicAdd(&cur1[dst1[i]], 1);
        esrc1[p] = src1[i];
    }
}

// ---------------- fused embedding mean: LDS tile-sort + fp8 gather -------
// Row = 128 fp8 = 128B = 32 lanes x uint. x0 stored fp8 scaled by X0S.
__global__ void embed_kernel(const int* __restrict__ user_word,
                             const unsigned char* __restrict__ wt8,
                             const int* __restrict__ degO0,
                             unsigned char* __restrict__ x0f) {
    __shared__ int raw[NPB * 50];
    __shared__ int srt[NPB * 50];
    __shared__ int cnt[NPB * 17];        // stride 17: avoids LDS bank conflicts
    int t = threadIdx.x;
    int base = blockIdx.x * NPB * 50;
    for (int j = t; j < NPB * 50; j += 256)
        raw[j] = user_word[base + j];
    for (int j = t; j < NPB * 17; j += 256)
        cnt[j] = 0;
    __syncthreads();
    if (t < NPB) {                                // 1 thread sorts 1 node (in LDS)
        int* c = cnt + t * 17;
        const int* r = raw + t * 50;
        for (int j = 0; j < 50; ++j) c[r[j] >> TILE_SHIFT]++;
        int run = 0;
        for (int b = 0; b < 13; ++b) { int v = c[b]; c[b] = run; run += v; }
        int* o = srt + t * 50;
        for (int j = 0; j < 50; ++j) { int v = r[j]; o[c[v >> TILE_SHIFT]++] = v; }
    }
    __syncthreads();
    int g = t >> 5, l = t & 31;                   // 8 groups of 32 lanes
    const unsigned* wt4 = (const unsigned*)wt8;   // row = 32 uints
    for (int n = g; n < NPB; n += 8) {            // 5 nodes per group
        const int* id = srt + n * 50;
        float a0 = 0.f, a1 = 0.f, a2 = 0.f, a3 = 0.f;
        #pragma unroll 2
        for (int j = 0; j < 50; j += 2) {         // 2 loads in flight
            unsigned v0 = wt4[id[j] * 32 + l];
            unsigned v1 = wt4[id[j + 1] * 32 + l];
            a0 += __builtin_amdgcn_cvt_f32_fp8(v0, 0) + __builtin_amdgcn_cvt_f32_fp8(v1, 0);
            a1 += __builtin_amdgcn_cvt_f32_fp8(v0, 1) + __builtin_amdgcn_cvt_f32_fp8(v1, 1);
            a2 += __builtin_amdgcn_cvt_f32_fp8(v0, 2) + __builtin_amdgcn_cvt_f32_fp8(v1, 2);
            a3 += __builtin_amdgcn_cvt_f32_fp8(v0, 3) + __builtin_amdgcn_cvt_f32_fp8(v1, 3);
        }
        int node = blockIdx.x * NPB + n;
        float s = rsqrtf(fmaxf((float)degO0[node], 1.0f)) * (0.02f * X0S); // 1/50 mean, fp8 scale
        ((unsigned*)x0f)[node * 32 + l] = pack4_fp8(a0 * s, a1 * s, a2 * s, a3 * s);
    }
}

// ---------------- layer-1 gather-aggregate (fp8 in, bf16 out, 1 wave/dst) ----------
__global__ void agg1_kernel(const int* __restrict__ off0, const int* __restrict__ esrc0,
                            const unsigned char* __restrict__ x0f,
                            unsigned short* __restrict__ agg1b) {
    int d = blockIdx.x;
    int t = threadIdx.x;               // 0..63
    int half = t >> 5, l = t & 31;
    int lo = off0[d], hi = off0[d + 1];
    const unsigned* x4 = (const unsigned*)x0f;     // row = 32 uints
    float a0 = 0.f, a1 = 0.f, a2 = 0.f, a3 = 0.f;
    for (int j = lo + half; j < hi; j += 2) {
        unsigned v = x4[esrc0[j] * 32 + l];
        a0 += __builtin_amdgcn_cvt_f32_fp8(v, 0);
        a1 += __builtin_amdgcn_cvt_f32_fp8(v, 1);
        a2 += __builtin_amdgcn_cvt_f32_fp8(v, 2);
        a3 += __builtin_amdgcn_cvt_f32_fp8(v, 3);
    }
    a0 += __shfl_down(a0, 32); a1 += __shfl_down(a1, 32);
    a2 += __shfl_down(a2, 32); a3 += __shfl_down(a3, 32);
    if (half == 0) {
        float sc = rsqrtf(fmaxf((float)(hi - lo), 1.0f)) * (1.0f / X0S);
        uint2 o; o.x = pack2(a0 * sc, a1 * sc); o.y = pack2(a2 * sc, a3 * sc);
        ((uint2*)agg1b)[d * 32 + l] = o;
    }
}

// ---------------- GEMM1 via MFMA: h1 = relu(agg1 @ W1 + b1) * rsqrt(degO1), fp8 out --
__global__ void gemm1_kernel(const unsigned short* __restrict__ agg1b,
                             const int* __restrict__ degO1,
                             const unsigned short* __restrict__ W1Tb,
                             const float* __restrict__ b1,
                             unsigned char* __restrict__ h1f) {
    __shared__ float s_out[16];
    int t = threadIdx.x;
    int row0 = blockIdx.x * 16;
    if (t < 16) s_out[t] = rsqrtf(fmaxf((float)degO1[row0 + t], 1.0f)) * H1S;
    __syncthreads();
    int w = t >> 6, lane = t & 63;
    int m = lane & 15, quad = lane >> 4;
    const unsigned short* abase = agg1b + (row0 + m) * 128 + quad * 8;
    bf16x8 afr[4];
    #pragma unroll
    for (int ks = 0; ks < 4; ++ks)
        afr[ks] = *(const bf16x8*)(abase + ks * 32);
    #pragma unroll
    for (int ct = 0; ct < 4; ++ct) {
        int gcol0 = (w * 4 + ct) * 16;
        const unsigned short* bbase = W1Tb + (gcol0 + m) * 128 + quad * 8;
        f32x4 acc = {0.f, 0.f, 0.f, 0.f};
        #pragma unroll
        for (int ks = 0; ks < 4; ++ks) {
            bf16x8 bfr = *(const bf16x8*)(bbase + ks * 32);
            acc = __builtin_amdgcn_mfma_f32_16x16x32_bf16(afr[ks], bfr, acc, 0, 0, 0);
        }
        int gcol = gcol0 + m;
        float bb = b1[gcol];
        #pragma unroll
        for (int reg = 0; reg < 4; ++reg) {
            int row = quad * 4 + reg;
            h1f[(row0 + row) * 256 + gcol] = f2fp8(fmaxf(acc[reg] + bb, 0.f) * s_out[row]);
        }
    }
}

// ---------------- layer-2 gather-aggregate (fp8 in, bf16 out, 1 wave/dst) -----------
// Row = 256 fp8 = 256B = 64 lanes x uint.
__global__ void agg2_kernel(const int* __restrict__ off1, const int* __restrict__ esrc1,
                            const unsigned char* __restrict__ h1f,
                            unsigned short* __restrict__ agg2b) {
    int d = blockIdx.x;
    int l = threadIdx.x;               // 0..63
    int lo = off1[d], hi = off1[d + 1];
    const unsigned* h4 = (const unsigned*)h1f;     // row = 64 uints
    float a0 = 0.f, a1 = 0.f, a2 = 0.f, a3 = 0.f;
    int j = lo;
    for (; j + 1 < hi; j += 2) {
        unsigned v0 = h4[esrc1[j] * 64 + l];
        unsigned v1 = h4[esrc1[j + 1] * 64 + l];
        a0 += __builtin_amdgcn_cvt_f32_fp8(v0, 0) + __builtin_amdgcn_cvt_f32_fp8(v1, 0);
        a1 += __builtin_amdgcn_cvt_f32_fp8(v0, 1) + __builtin_amdgcn_cvt_f32_fp8(v1, 1);
        a2 += __builtin_amdgcn_cvt_f32_fp8(v0, 2) + __builtin_amdgcn_cvt_f32_fp8(v1, 2);
        a3 += __builtin_amdgcn_cvt_f32_fp8(v0, 3) + __builtin_amdgcn_cvt_f32_fp8(v1, 3);
    }
    if (j < hi) {
        unsigned v = h4[esrc1[j] * 64 + l];
        a0 += __builtin_amdgcn_cvt_f32_fp8(v, 0);
        a1 += __builtin_amdgcn_cvt_f32_fp8(v, 1);
        a2 += __builtin_amdgcn_cvt_f32_fp8(v, 2);
        a3 += __builtin_amdgcn_cvt_f32_fp8(v, 3);
    }
    float sc = rsqrtf(fmaxf((float)(hi - lo), 1.0f)) * (1.0f / H1S);
    uint2 o; o.x = pack2(a0 * sc, a1 * sc); o.y = pack2(a2 * sc, a3 * sc);
    ((uint2*)agg2b)[d * 64 + l] = o;
}

// ---------------- GEMM2 via MFMA: out = relu(agg2 @ W2 + b2) (+ labels) --------------
__global__ void gemm2_kernel(const unsigned short* __restrict__ agg2b,
                             const unsigned short* __restrict__ W2Tb,
                             const float* __restrict__ b2,
                             const int* __restrict__ labels,
                             float* __restrict__ out) {
    int lane = threadIdx.x;            // 0..63
    int row0 = blockIdx.x * 16;
    int m = lane & 15, quad = lane >> 4;
    int arow = min(row0 + m, NDST1 - 1);           // clamp OOB reads (last block)
    const unsigned short* abase = agg2b + arow * 256 + quad * 8;
    const unsigned short* bbase = W2Tb + m * 256 + quad * 8;
    f32x4 acc = {0.f, 0.f, 0.f, 0.f};
    #pragma unroll
    for (int ks = 0; ks < 8; ++ks) {
        bf16x8 af = *(const bf16x8*)(abase + ks * 32);
        bf16x8 bf = *(const bf16x8*)(bbase + ks * 32);
        acc = __builtin_amdgcn_mfma_f32_16x16x32_bf16(af, bf, acc, 0, 0, 0);
    }
    float bb = b2[m];
    #pragma unroll
    for (int reg = 0; reg < 4; ++reg) {
        int row = row0 + quad * 4 + reg;
        if (row < NDST1)
            out[row * NOUT + m] = fmaxf(acc[reg] + bb, 0.f);
    }
    if (lane < 16 && row0 + lane < NDST1)
        out[NDST1 * NOUT + row0 + lane] = (float)labels[row0 + lane];
}

extern "C" void kernel_launch(void* const* d_in, const int* in_sizes, int n_in,
                              void* d_out, int out_size, void* d_ws, size_t ws_size,
                              hipStream_t stream) {
    const int*   user_word  = (const int*)d_in[0];
    const int*   labels     = (const int*)d_in[1];
    const int*   src0       = (const int*)d_in[2];
    const int*   dst0       = (const int*)d_in[3];
    const int*   src1       = (const int*)d_in[4];
    const int*   dst1       = (const int*)d_in[5];
    const float* word_table = (const float*)d_in[6];
    const float* W1         = (const float*)d_in[7];
    const float* b1         = (const float*)d_in[8];
    const float* W2         = (const float*)d_in[9];
    const float* b2         = (const float*)d_in[10];

    int* iws = (int*)d_ws;
    int* cnt0  = iws;            // 20000  ┐
    int* cnt1  = iws + 20000;    //  5000  │ zeroed (95000 ints)
    int* degO0 = iws + 25000;    // 50000  │
    int* degO1 = iws + 75000;    // 20000  ┘
    int* off0  = iws + 95000;    // 20001
    int* off1  = iws + 115001;   //  5001
    int* cur0  = iws + 120002;   // 20000
    int* cur1  = iws + 140002;   //  5000
    int* esrc0 = iws + 145002;   // 300000
    int* esrc1 = iws + 445002;   // 75000   (end 520002; pad to 520004)
    unsigned char*  wt8   = (unsigned char*)(iws + 520004);   // 6.4M fp8  = 1.6M ints
    unsigned char*  x0f   = (unsigned char*)(iws + 2120004);  // 6.4M fp8  = 1.6M ints
    unsigned char*  h1f   = (unsigned char*)(iws + 3720004);  // 5.12M fp8 = 1.28M ints
    unsigned short* agg1b = (unsigned short*)(iws + 5000004); // 2.56M bf16 = 1.28M ints
    unsigned short* agg2b = (unsigned short*)(iws + 6280004); // 1.28M bf16 = 640K ints
    unsigned short* W1Tb  = (unsigned short*)(iws + 6920004); // 32768 bf16
    unsigned short* W2Tb  = (unsigned short*)(iws + 6936388); // 4096 bf16 (end ≈ 27.8 MB)

    hipMemsetAsync(iws, 0, 95000 * sizeof(int), stream);

    prep_kernel<<<(NSRC0 * EMB / 8 + 255) / 256, 256, 0, stream>>>(
        word_table, wt8, W1, W1Tb, W2, W2Tb,
        src0, dst0, src1, dst1, cnt0, cnt1, degO0, degO1);
    scan_kernel<<<2, 1024, 0, stream>>>(cnt0, off0, cur0, cnt1, off1, cur1);
    bucket_kernel<<<(E0 + 255) / 256, 256, 0, stream>>>(src0, dst0, src1, dst1,
                                                        cur0, cur1, esrc0, esrc1);
    embed_kernel<<<NSRC0 / NPB, 256, 0, stream>>>(user_word, wt8, degO0, x0f);
    agg1_kernel<<<NDST0, 64, 0, stream>>>(off0, esrc0, x0f, agg1b);
    gemm1_kernel<<<NDST0 / 16, 256, 0, stream>>>(agg1b, degO1, W1Tb, b1, h1f);
    agg2_kernel<<<NDST1, 64, 0, stream>>>(off1, esrc1, h1f, agg2b);
    gemm2_kernel<<<(NDST1 + 15) / 16, 64, 0, stream>>>(agg2b, W2Tb, b2, labels, (float*)d_out);
}

// Round 14
// 280.239 us; speedup vs baseline: 1.2344x; 1.0203x over previous
//
#include <hip/hip_runtime.h>

#define E0     300000
#define E1     75000
#define NSRC0  50000
#define NDST0  20000
#define NDST1  5000
#define EMB    128
#define HID    256
#define NOUT   16

#define NPB        40     // nodes per embed block (1250 * 40 = 50000 exactly)
#define TILE_SHIFT 12     // 4096-row vocab tiles; tiles 0..12
#define NEMB_BLK   (NSRC0 / NPB)          // 1250
#define NBKT_BLK   ((E0 + 255) / 256)     // 1172

#define X0S  32.0f        // fp8 pre-scale for x0  (undone in agg1)
#define H1S  64.0f        // fp8 pre-scale for h1  (undone in agg2)

typedef __attribute__((ext_vector_type(8))) short bf16x8;   // MFMA A/B frag (4 VGPRs)
typedef __attribute__((ext_vector_type(4))) float f32x4;    // MFMA C/D frag
typedef __attribute__((ext_vector_type(2))) float f32x2;

// ---- bf16 helpers ----
__device__ __forceinline__ unsigned short f2bf(float f) {
    unsigned u = __float_as_uint(f);
    return (unsigned short)((u + 0x7FFFu + ((u >> 16) & 1u)) >> 16);
}
__device__ __forceinline__ unsigned pack2(float a, float b) {
    return (unsigned)f2bf(a) | ((unsigned)f2bf(b) << 16);
}
// ---- fp8 e4m3 helpers (HW cvt) ----
__device__ __forceinline__ unsigned pack4_fp8(float a0, float a1, float a2, float a3) {
    unsigned p = 0;
    p = __builtin_amdgcn_cvt_pk_fp8_f32(a0, a1, p, false);   // bytes 0,1
    p = __builtin_amdgcn_cvt_pk_fp8_f32(a2, a3, p, true);    // bytes 2,3
    return p;
}
__device__ __forceinline__ unsigned char f2fp8(float v) {
    unsigned p = __builtin_amdgcn_cvt_pk_fp8_f32(v, v, 0, false);
    return (unsigned char)(p & 0xFF);
}
// unpack 4 fp8 bytes -> two float2 (packed HW cvt when available)
#if __has_builtin(__builtin_amdgcn_cvt_pk_f32_fp8)
__device__ __forceinline__ f32x2 up_lo(unsigned v) { return __builtin_amdgcn_cvt_pk_f32_fp8(v, false); }
__device__ __forceinline__ f32x2 up_hi(unsigned v) { return __builtin_amdgcn_cvt_pk_f32_fp8(v, true); }
#else
__device__ __forceinline__ f32x2 up_lo(unsigned v) {
    f32x2 r; r.x = __builtin_amdgcn_cvt_f32_fp8(v, 0); r.y = __builtin_amdgcn_cvt_f32_fp8(v, 1); return r;
}
__device__ __forceinline__ f32x2 up_hi(unsigned v) {
    f32x2 r; r.x = __builtin_amdgcn_cvt_f32_fp8(v, 2); r.y = __builtin_amdgcn_cvt_f32_fp8(v, 3); return r;
}
#endif

// ---------------- prep: table->fp8, W1^T/W2^T->bf16, degree histograms ----------------
__global__ void prep_kernel(const float* __restrict__ wt, unsigned char* __restrict__ wt8,
                            const float* __restrict__ W1, unsigned short* __restrict__ W1Tb,
                            const float* __restrict__ W2, unsigned short* __restrict__ W2Tb,
                            const int* __restrict__ src0, const int* __restrict__ dst0,
                            const int* __restrict__ src1, const int* __restrict__ dst1,
                            int* cnt0, int* cnt1, int* degO0, int* degO1) {
    int i = blockIdx.x * blockDim.x + threadIdx.x;
    if (i < NSRC0 * EMB / 8) {            // 800000: pack 8 floats -> 8 fp8
        const float4* in = (const float4*)wt;
        float4 v0 = in[i * 2], v1 = in[i * 2 + 1];
        uint2 o;
        o.x = pack4_fp8(v0.x, v0.y, v0.z, v0.w);
        o.y = pack4_fp8(v1.x, v1.y, v1.z, v1.w);
        ((uint2*)wt8)[i] = o;
    }
    if (i < EMB * HID) {                  // W1[128][256] -> W1T bf16 [256][128]
        int n = i & 255, k = i >> 8;
        W1Tb[n * 128 + k] = f2bf(W1[i]);
    }
    if (i < HID * NOUT) {                 // W2[256][16] -> W2T bf16 [16][256]
        int n = i & 15, k = i >> 4;
        W2Tb[n * 256 + k] = f2bf(W2[i]);
    }
    if (i < E0) {
        atomicAdd(&cnt0[dst0[i]], 1);
        atomicAdd(&degO0[src0[i]], 1);
    }
    if (i < E1) {
        atomicAdd(&cnt1[dst1[i]], 1);
        atomicAdd(&degO1[src1[i]], 1);
    }
}

// ---------------- exclusive scan (2 blocks x 1024 threads, own dispatch) --------------
__device__ void scan_body(const int* __restrict__ cnt, int n,
                          int* __restrict__ off, int* __restrict__ cur) {
    __shared__ int sums[1024];
    int t = threadIdx.x;
    int chunk = (n + 1023) / 1024;
    int lo = t * chunk, hi = min(lo + chunk, n);
    int s = 0;
    for (int i = lo; i < hi; ++i) s += cnt[i];
    sums[t] = s;
    __syncthreads();
    for (int d = 1; d < 1024; d <<= 1) {
        int x = (t >= d) ? sums[t - d] : 0;
        __syncthreads();
        sums[t] += x;
        __syncthreads();
    }
    int run = (t == 0) ? 0 : sums[t - 1];
    for (int i = lo; i < hi; ++i) {
        off[i] = run; cur[i] = run;
        run += cnt[i];
    }
    if (t == 1023) off[n] = run;
}

__global__ void scan_kernel(const int* cnt0, int* off0, int* cur0,
                            const int* cnt1, int* off1, int* cur1) {
    if (blockIdx.x == 0) scan_body(cnt0, NDST0, off0, cur0);
    else                 scan_body(cnt1, NDST1, off1, cur1);
}

// ---------------- embed (blocks 0..1249) + edge bucket (blocks 1250..2421) fused ------
// Bucket blocks are short & uniform -> they hide in embed's latency-bound shadow
// (unlike r12's serial-chain scan, which straggled).
__global__ void embed_bucket_kernel(const int* __restrict__ user_word,
                                    const unsigned char* __restrict__ wt8,
                                    const int* __restrict__ degO0,
                                    unsigned char* __restrict__ x0f,
                                    const int* __restrict__ src0, const int* __restrict__ dst0,
                                    const int* __restrict__ src1, const int* __restrict__ dst1,
                                    int* cur0, int* cur1, int* esrc0, int* esrc1) {
    if (blockIdx.x >= NEMB_BLK) {        // ---- bucket part ----
        int i = (blockIdx.x - NEMB_BLK) * 256 + threadIdx.x;
        if (i < E0) {
            int p = atomicAdd(&cur0[dst0[i]], 1);
            esrc0[p] = src0[i];
        }
        if (i < E1) {
            int p = atomicAdd(&cur1[dst1[i]], 1);
            esrc1[p] = src1[i];
        }
        return;
    }
    // ---- embed part ----
    __shared__ int raw[NPB * 50];
    __shared__ int srt[NPB * 50];
    __shared__ int cnt[NPB * 17];        // stride 17: avoids LDS bank conflicts
    int t = threadIdx.x;
    int base = blockIdx.x * NPB * 50;
    for (int j = t; j < NPB * 50; j += 256)
        raw[j] = user_word[base + j];
    for (int j = t; j < NPB * 17; j += 256)
        cnt[j] = 0;
    __syncthreads();
    if (t < NPB) {                                // 1 thread sorts 1 node (in LDS)
        int* c = cnt + t * 17;
        const int* r = raw + t * 50;
        for (int j = 0; j < 50; ++j) c[r[j] >> TILE_SHIFT]++;
        int run = 0;
        for (int b = 0; b < 13; ++b) { int v = c[b]; c[b] = run; run += v; }
        int* o = srt + t * 50;
        for (int j = 0; j < 50; ++j) { int v = r[j]; o[c[v >> TILE_SHIFT]++] = v; }
    }
    __syncthreads();
    int g = t >> 5, l = t & 31;                   // 8 groups of 32 lanes
    const unsigned* wt4 = (const unsigned*)wt8;   // row = 32 uints
    for (int n = g; n < NPB; n += 8) {            // 5 nodes per group
        const int* id = srt + n * 50;
        f32x2 a01 = {0.f, 0.f}, a23 = {0.f, 0.f};
        #pragma unroll 2
        for (int j = 0; j < 50; j += 2) {         // 2 loads in flight
            unsigned v0 = wt4[id[j] * 32 + l];
            unsigned v1 = wt4[id[j + 1] * 32 + l];
            a01 += up_lo(v0) + up_lo(v1);
            a23 += up_hi(v0) + up_hi(v1);
        }
        int node = blockIdx.x * NPB + n;
        float s = rsqrtf(fmaxf((float)degO0[node], 1.0f)) * (0.02f * X0S); // 1/50 mean, fp8 scale
        ((unsigned*)x0f)[node * 32 + l] = pack4_fp8(a01.x * s, a01.y * s, a23.x * s, a23.y * s);
    }
}

// ---------------- layer-1 gather-aggregate (fp8 in, bf16 out, 1 wave/dst) ----------
__global__ void agg1_kernel(const int* __restrict__ off0, const int* __restrict__ esrc0,
                            const unsigned char* __restrict__ x0f,
                            unsigned short* __restrict__ agg1b) {
    int d = blockIdx.x;
    int t = threadIdx.x;               // 0..63
    int half = t >> 5, l = t & 31;
    int lo = off0[d], hi = off0[d + 1];
    const unsigned* x4 = (const unsigned*)x0f;     // row = 32 uints
    f32x2 a01 = {0.f, 0.f}, a23 = {0.f, 0.f};
    for (int j = lo + half; j < hi; j += 2) {
        unsigned v = x4[esrc0[j] * 32 + l];
        a01 += up_lo(v); a23 += up_hi(v);
    }
    a01.x += __shfl_down(a01.x, 32); a01.y += __shfl_down(a01.y, 32);
    a23.x += __shfl_down(a23.x, 32); a23.y += __shfl_down(a23.y, 32);
    if (half == 0) {
        float sc = rsqrtf(fmaxf((float)(hi - lo), 1.0f)) * (1.0f / X0S);
        uint2 o; o.x = pack2(a01.x * sc, a01.y * sc); o.y = pack2(a23.x * sc, a23.y * sc);
        ((uint2*)agg1b)[d * 32 + l] = o;
    }
}

// ---------------- GEMM1 via MFMA: h1 = relu(agg1 @ W1 + b1) * rsqrt(degO1), fp8 out --
__global__ void gemm1_kernel(const unsigned short* __restrict__ agg1b,
                             const int* __restrict__ degO1,
                             const unsigned short* __restrict__ W1Tb,
                             const float* __restrict__ b1,
                             unsigned char* __restrict__ h1f) {
    __shared__ float s_out[16];
    int t = threadIdx.x;
    int row0 = blockIdx.x * 16;
    if (t < 16) s_out[t] = rsqrtf(fmaxf((float)degO1[row0 + t], 1.0f)) * H1S;
    __syncthreads();
    int w = t >> 6, lane = t & 63;
    int m = lane & 15, quad = lane >> 4;
    const unsigned short* abase = agg1b + (row0 + m) * 128 + quad * 8;
    bf16x8 afr[4];
    #pragma unroll
    for (int ks = 0; ks < 4; ++ks)
        afr[ks] = *(const bf16x8*)(abase + ks * 32);
    #pragma unroll
    for (int ct = 0; ct < 4; ++ct) {
        int gcol0 = (w * 4 + ct) * 16;
        const unsigned short* bbase = W1Tb + (gcol0 + m) * 128 + quad * 8;
        f32x4 acc = {0.f, 0.f, 0.f, 0.f};
        #pragma unroll
        for (int ks = 0; ks < 4; ++ks) {
            bf16x8 bfr = *(const bf16x8*)(bbase + ks * 32);
            acc = __builtin_amdgcn_mfma_f32_16x16x32_bf16(afr[ks], bfr, acc, 0, 0, 0);
        }
        int gcol = gcol0 + m;
        float bb = b1[gcol];
        #pragma unroll
        for (int reg = 0; reg < 4; ++reg) {
            int row = quad * 4 + reg;
            h1f[(row0 + row) * 256 + gcol] = f2fp8(fmaxf(acc[reg] + bb, 0.f) * s_out[row]);
        }
    }
}

// ---------------- layer-2 gather-aggregate (fp8 in, bf16 out, 1 wave/dst) -----------
__global__ void agg2_kernel(const int* __restrict__ off1, const int* __restrict__ esrc1,
                            const unsigned char* __restrict__ h1f,
                            unsigned short* __restrict__ agg2b) {
    int d = blockIdx.x;
    int l = threadIdx.x;               // 0..63
    int lo = off1[d], hi = off1[d + 1];
    const unsigned* h4 = (const unsigned*)h1f;     // row = 64 uints
    f32x2 a01 = {0.f, 0.f}, a23 = {0.f, 0.f};
    int j = lo;
    for (; j + 1 < hi; j += 2) {
        unsigned v0 = h4[esrc1[j] * 64 + l];
        unsigned v1 = h4[esrc1[j + 1] * 64 + l];
        a01 += up_lo(v0) + up_lo(v1);
        a23 += up_hi(v0) + up_hi(v1);
    }
    if (j < hi) {
        unsigned v = h4[esrc1[j] * 64 + l];
        a01 += up_lo(v); a23 += up_hi(v);
    }
    float sc = rsqrtf(fmaxf((float)(hi - lo), 1.0f)) * (1.0f / H1S);
    uint2 o; o.x = pack2(a01.x * sc, a01.y * sc); o.y = pack2(a23.x * sc, a23.y * sc);
    ((uint2*)agg2b)[d * 64 + l] = o;
}

// ---------------- GEMM2 via MFMA: out = relu(agg2 @ W2 + b2) (+ labels) --------------
__global__ void gemm2_kernel(const unsigned short* __restrict__ agg2b,
                             const unsigned short* __restrict__ W2Tb,
                             const float* __restrict__ b2,
                             const int* __restrict__ labels,
                             float* __restrict__ out) {
    int lane = threadIdx.x;            // 0..63
    int row0 = blockIdx.x * 16;
    int m = lane & 15, quad = lane >> 4;
    int arow = min(row0 + m, NDST1 - 1);           // clamp OOB reads (last block)
    const unsigned short* abase = agg2b + arow * 256 + quad * 8;
    const unsigned short* bbase = W2Tb + m * 256 + quad * 8;
    f32x4 acc = {0.f, 0.f, 0.f, 0.f};
    #pragma unroll
    for (int ks = 0; ks < 8; ++ks) {
        bf16x8 af = *(const bf16x8*)(abase + ks * 32);
        bf16x8 bf = *(const bf16x8*)(bbase + ks * 32);
        acc = __builtin_amdgcn_mfma_f32_16x16x32_bf16(af, bf, acc, 0, 0, 0);
    }
    float bb = b2[m];
    #pragma unroll
    for (int reg = 0; reg < 4; ++reg) {
        int row = row0 + quad * 4 + reg;
        if (row < NDST1)
            out[row * NOUT + m] = fmaxf(acc[reg] + bb, 0.f);
    }
    if (lane < 16 && row0 + lane < NDST1)
        out[NDST1 * NOUT + row0 + lane] = (float)labels[row0 + lane];
}

extern "C" void kernel_launch(void* const* d_in, const int* in_sizes, int n_in,
                              void* d_out, int out_size, void* d_ws, size_t ws_size,
                              hipStream_t stream) {
    const int*   user_word  = (const int*)d_in[0];
    const int*   labels     = (const int*)d_in[1];
    const int*   src0       = (const int*)d_in[2];
    const int*   dst0       = (const int*)d_in[3];
    const int*   src1       = (const int*)d_in[4];
    const int*   dst1       = (const int*)d_in[5];
    const float* word_table = (const float*)d_in[6];
    const float* W1         = (const float*)d_in[7];
    const float* b1         = (const float*)d_in[8];
    const float* W2         = (const float*)d_in[9];
    const float* b2         = (const float*)d_in[10];

    int* iws = (int*)d_ws;
    int* cnt0  = iws;            // 20000  ┐
    int* cnt1  = iws + 20000;    //  5000  │ zeroed (95000 ints)
    int* degO0 = iws + 25000;    // 50000  │
    int* degO1 = iws + 75000;    // 20000  ┘
    int* off0  = iws + 95000;    // 20001
    int* off1  = iws + 115001;   //  5001
    int* cur0  = iws + 120002;   // 20000
    int* cur1  = iws + 140002;   //  5000
    int* esrc0 = iws + 145002;   // 300000
    int* esrc1 = iws + 445002;   // 75000   (end 520002; pad to 520004)
    unsigned char*  wt8   = (unsigned char*)(iws + 520004);   // 6.4M fp8  = 1.6M ints
    unsigned char*  x0f   = (unsigned char*)(iws + 2120004);  // 6.4M fp8  = 1.6M ints
    unsigned char*  h1f   = (unsigned char*)(iws + 3720004);  // 5.12M fp8 = 1.28M ints
    unsigned short* agg1b = (unsigned short*)(iws + 5000004); // 2.56M bf16 = 1.28M ints
    unsigned short* agg2b = (unsigned short*)(iws + 6280004); // 1.28M bf16 = 640K ints
    unsigned short* W1Tb  = (unsigned short*)(iws + 6920004); // 32768 bf16
    unsigned short* W2Tb  = (unsigned short*)(iws + 6936388); // 4096 bf16 (end ≈ 27.8 MB)

    hipMemsetAsync(iws, 0, 95000 * sizeof(int), stream);

    prep_kernel<<<(NSRC0 * EMB / 8 + 255) / 256, 256, 0, stream>>>(
        word_table, wt8, W1, W1Tb, W2, W2Tb,
        src0, dst0, src1, dst1, cnt0, cnt1, degO0, degO1);
    scan_kernel<<<2, 1024, 0, stream>>>(cnt0, off0, cur0, cnt1, off1, cur1);
    embed_bucket_kernel<<<NEMB_BLK + NBKT_BLK, 256, 0, stream>>>(
        user_word, wt8, degO0, x0f,
        src0, dst0, src1, dst1, cur0, cur1, esrc0, esrc1);
    agg1_kernel<<<NDST0, 64, 0, stream>>>(off0, esrc0, x0f, agg1b);
    gemm1_kernel<<<NDST0 / 16, 256, 0, stream>>>(agg1b, degO1, W1Tb, b1, h1f);
    agg2_kernel<<<NDST1, 64, 0, stream>>>(off1, esrc1, h1f, agg2b);
    gemm2_kernel<<<(NDST1 + 15) / 16, 64, 0, stream>>>(agg2b, W2Tb, b2, labels, (float*)d_out);
}